// Round 2
// baseline (608.092 us; speedup 1.0000x reference)
//
#include <hip/hip_runtime.h>
#include <hip/hip_bf16.h>
#include <hip/hip_cooperative_groups.h>
#include <stdint.h>

namespace cg = cooperative_groups;

#define V 50257
#define E 1024
#define H 1024
#define L 52

// mega-kernel geometry: 256 blocks x 512 threads = 2048 waves (8 waves/CU)
#define NB 256
#define NT 512
#define NWAVE 2048

// fallback atomic slots
#define NSLOT 64
#define SLOT_STRIDE 8

// ---------- helpers ----------
__device__ __forceinline__ float bf_lo(uint32_t u) { return __uint_as_float(u << 16); }
__device__ __forceinline__ float bf_hi(uint32_t u) { return __uint_as_float(u & 0xffff0000u); }

__device__ __forceinline__ float dot4(float4 a, float4 b) {
    return a.x * b.x + a.y * b.y + a.z * b.z + a.w * b.w;
}
__device__ __forceinline__ float dot8f(uint4 u, float4 a, float4 b) {
    return bf_lo(u.x) * a.x + bf_hi(u.x) * a.y + bf_lo(u.y) * a.z + bf_hi(u.y) * a.w +
           bf_lo(u.z) * b.x + bf_hi(u.z) * b.y + bf_lo(u.w) * b.z + bf_hi(u.w) * b.w;
}
__device__ __forceinline__ float dot8bb(uint4 u, uint4 v) {
    return bf_lo(u.x) * bf_lo(v.x) + bf_hi(u.x) * bf_hi(v.x) +
           bf_lo(u.y) * bf_lo(v.y) + bf_hi(u.y) * bf_hi(v.y) +
           bf_lo(u.z) * bf_lo(v.z) + bf_hi(u.z) * bf_hi(v.z) +
           bf_lo(u.w) * bf_lo(v.w) + bf_hi(u.w) * bf_hi(v.w);
}

__device__ __forceinline__ float wred(float v) {
#pragma unroll
    for (int o = 32; o; o >>= 1) v += __shfl_down(v, o, 64);
    return v;  // valid in lane 0
}

// Inline dtype detect (wave-uniform; full wave, no divergence).
__device__ __forceinline__ int detect_f32(const void* probe) {
    uint32_t u = ((const uint32_t*)probe)[threadIdx.x & 63];
    float lo = __uint_as_float(u << 16);
    int bad = (lo != lo) || (fabsf(lo) > 100.f);
    unsigned long long m = __ballot(bad);
    return (__popcll(m) > 4) ? 1 : 0;
}

// =====================================================================
// MEGA KERNEL (cooperative): all stages, 5 grid syncs.
// ws layout (floats):
// [0..1024)    emb_lin        } cat2 contiguous
// [1024..2048) attn_app       }
// [2048..2112) attn_lg0 (52)
// [2112..3136) xvec
// [3136..4160) hnew
// [4160..4416) S_parts (one per block, no atomics)
// [4416..7488) ghs: gh[j], gh[j+1024], gh[j+2048]  (whh@h0, hoisted to stage A)
// =====================================================================
__global__ __launch_bounds__(NT) void k_mega(
    const int* __restrict__ token, const void* __restrict__ h0,
    const void* __restrict__ enc, const void* __restrict__ embt,
    const void* __restrict__ linw, const void* __restrict__ linb,
    const void* __restrict__ attw, const void* __restrict__ attb,
    const void* __restrict__ combw, const void* __restrict__ combb,
    const void* __restrict__ wih, const void* __restrict__ whh,
    const void* __restrict__ bih, const void* __restrict__ bhh,
    const void* __restrict__ outw, const void* __restrict__ outb,
    float* __restrict__ out, float* __restrict__ ws) {
    cg::grid_group grid = cg::this_grid();
    const int tid = threadIdx.x, lane = tid & 63, wid = tid >> 6;
    const int gw = (int)blockIdx.x * (NT / 64) + wid;  // 0..2047
    const int isf32 = detect_f32(embt);

    float* emb_lin = ws;
    float* attn_app = ws + 1024;
    float* attn_lg0 = ws + 2048;
    float* xvec = ws + 2112;
    float* hnew = ws + 3136;
    float* S_parts = ws + 4160;
    float* ghs = ws + 4416;

    __shared__ float s_lg[L], s_aw[L], s_part[NT / 64];

    // ---------------- Stage A: emb_lin rows, attn h0-half, gru gh-half ----------------
    if (gw < 1024) {
        const int h = gw;
        float acc = 0.f, bias;
        if (isf32) {
            const float4* e = (const float4*)((const float*)embt + (size_t)token[0] * E);
            const float4* w = (const float4*)((const float*)linw + (size_t)h * E);
#pragma unroll
            for (int k = lane; k < 256; k += 64) acc += dot4(w[k], e[k]);
            bias = ((const float*)linb)[h];
        } else {
            const uint4* e = (const uint4*)((const __hip_bfloat16*)embt + (size_t)token[0] * E);
            const uint4* w = (const uint4*)((const __hip_bfloat16*)linw + (size_t)h * E);
#pragma unroll
            for (int k = lane; k < 128; k += 64) acc += dot8bb(w[k], e[k]);
            bias = __bfloat162float(((const __hip_bfloat16*)linb)[h]);
        }
        acc = wred(acc);
        if (lane == 0) emb_lin[h] = acc + bias;
        if (gw < L) {  // attn logits h0-half (extra task for first 52 waves)
            const int l = gw;
            float acc2 = 0.f, bias2;
            if (isf32) {
                const float4* w = (const float4*)((const float*)attw + (size_t)l * 2 * H + H);
                const float4* h0f = (const float4*)(const float*)h0;
#pragma unroll
                for (int k = lane; k < 256; k += 64) acc2 += dot4(w[k], h0f[k]);
                bias2 = ((const float*)attb)[l];
            } else {
                const uint4* w = (const uint4*)((const __hip_bfloat16*)attw + (size_t)l * 2 * H + H);
                const uint4* h0u = (const uint4*)(const __hip_bfloat16*)h0;
#pragma unroll
                for (int k = lane; k < 128; k += 64) acc2 += dot8bb(w[k], h0u[k]);
                bias2 = __bfloat162float(((const __hip_bfloat16*)attb)[l]);
            }
            acc2 = wred(acc2);
            if (lane == 0) attn_lg0[l] = acc2 + bias2;
        }
    } else {
        const int j = gw - 1024;  // gru gh-half: independent of all other stages
        float b0 = 0, b1 = 0, b2 = 0;
        if (isf32) {
            const float* wh = (const float*)whh;
            const float4* wh0 = (const float4*)(wh + (size_t)j * H);
            const float4* wh1 = (const float4*)(wh + (size_t)(j + H) * H);
            const float4* wh2 = (const float4*)(wh + (size_t)(j + 2 * H) * H);
            const float4* h0f = (const float4*)(const float*)h0;
#pragma unroll
            for (int k = lane; k < 256; k += 64) {
                float4 hv = h0f[k];
                b0 += dot4(wh0[k], hv); b1 += dot4(wh1[k], hv); b2 += dot4(wh2[k], hv);
            }
        } else {
            const __hip_bfloat16* wh = (const __hip_bfloat16*)whh;
            const uint4* wh0 = (const uint4*)(wh + (size_t)j * H);
            const uint4* wh1 = (const uint4*)(wh + (size_t)(j + H) * H);
            const uint4* wh2 = (const uint4*)(wh + (size_t)(j + 2 * H) * H);
            const uint4* h0u = (const uint4*)(const __hip_bfloat16*)h0;
#pragma unroll
            for (int k = lane; k < 128; k += 64) {
                uint4 hv = h0u[k];
                b0 += dot8bb(wh0[k], hv); b1 += dot8bb(wh1[k], hv); b2 += dot8bb(wh2[k], hv);
            }
        }
        b0 = wred(b0); b1 = wred(b1); b2 = wred(b2);
        if (lane == 0) { ghs[j] = b0; ghs[j + 1024] = b1; ghs[j + 2048] = b2; }
    }
    grid.sync();

    // ---------------- Stage B: attn emb-half + softmax + context (block 0) ----------------
    if (blockIdx.x == 0) {
        const float4* ef = (const float4*)emb_lin;
        for (int l = wid; l < L; l += NT / 64) {
            float acc = 0.f;
            if (isf32) {
                const float4* w = (const float4*)((const float*)attw + (size_t)l * 2 * H);
#pragma unroll
                for (int k = lane; k < 256; k += 64) acc += dot4(w[k], ef[k]);
            } else {
                const uint4* w = (const uint4*)((const __hip_bfloat16*)attw + (size_t)l * 2 * H);
#pragma unroll
                for (int k = lane; k < 128; k += 64) acc += dot8f(w[k], ef[2 * k], ef[2 * k + 1]);
            }
            acc = wred(acc);
            if (lane == 0) s_lg[l] = acc + attn_lg0[l];
        }
        __syncthreads();
        if (tid < 64) {  // wave-parallel softmax over 52 logits
            float x = (tid < L) ? s_lg[tid] : -1e30f;
            float m = x;
#pragma unroll
            for (int o = 32; o; o >>= 1) m = fmaxf(m, __shfl_down(m, o, 64));
            m = __shfl(m, 0, 64);
            float e = (tid < L) ? expf(x - m) : 0.f;
            float s = e;
#pragma unroll
            for (int o = 32; o; o >>= 1) s += __shfl_down(s, o, 64);
            s = __shfl(s, 0, 64);
            if (tid < L) s_aw[tid] = e / s;
        }
        __syncthreads();
        if (tid < L) out[(size_t)V + H + tid] = s_aw[tid];
        for (int h = tid; h < H; h += NT) {
            float acc = 0.f;
            if (isf32) {
                const float* e = (const float*)enc;
                for (int l = 0; l < L; l++) acc += s_aw[l] * e[l * H + h];
            } else {
                const __hip_bfloat16* e = (const __hip_bfloat16*)enc;
                for (int l = 0; l < L; l++) acc += s_aw[l] * __bfloat162float(e[l * H + h]);
            }
            attn_app[h] = acc;
        }
    }
    grid.sync();

    // ---------------- Stage C: x = relu(cat(emb, attn_app) @ comb_w.T + b) ----------------
    if (gw < 1024) {
        const int h = gw;
        const float4* cf = (const float4*)ws;  // cat2
        float acc = 0.f, bias;
        if (isf32) {
            const float4* w = (const float4*)((const float*)combw + (size_t)h * 2 * H);
#pragma unroll
            for (int k = lane; k < 512; k += 64) acc += dot4(w[k], cf[k]);
            bias = ((const float*)combb)[h];
        } else {
            const uint4* w = (const uint4*)((const __hip_bfloat16*)combw + (size_t)h * 2 * H);
#pragma unroll
            for (int k = lane; k < 256; k += 64) acc += dot8f(w[k], cf[2 * k], cf[2 * k + 1]);
            bias = __bfloat162float(((const __hip_bfloat16*)combb)[h]);
        }
        acc = wred(acc);
        if (lane == 0) xvec[h] = fmaxf(acc + bias, 0.f);
    }
    grid.sync();

    // ---------------- Stage D: gru gi-half + combine ----------------
    if (gw < 1024) {
        const int j = gw;
        const float4* xf = (const float4*)xvec;
        float a0 = 0, a1 = 0, a2 = 0;
        if (isf32) {
            const float* wi = (const float*)wih;
            const float4* wi0 = (const float4*)(wi + (size_t)j * H);
            const float4* wi1 = (const float4*)(wi + (size_t)(j + H) * H);
            const float4* wi2 = (const float4*)(wi + (size_t)(j + 2 * H) * H);
#pragma unroll
            for (int k = lane; k < 256; k += 64) {
                float4 xa = xf[k];
                a0 += dot4(wi0[k], xa); a1 += dot4(wi1[k], xa); a2 += dot4(wi2[k], xa);
            }
        } else {
            const __hip_bfloat16* wi = (const __hip_bfloat16*)wih;
            const uint4* wi0 = (const uint4*)(wi + (size_t)j * H);
            const uint4* wi1 = (const uint4*)(wi + (size_t)(j + H) * H);
            const uint4* wi2 = (const uint4*)(wi + (size_t)(j + 2 * H) * H);
#pragma unroll
            for (int k = lane; k < 128; k += 64) {
                float4 xa = xf[2 * k], xb = xf[2 * k + 1];
                a0 += dot8f(wi0[k], xa, xb); a1 += dot8f(wi1[k], xa, xb); a2 += dot8f(wi2[k], xa, xb);
            }
        }
        a0 = wred(a0); a1 = wred(a1); a2 = wred(a2);
        if (lane == 0) {
            float bi0, bi1, bi2, bh0, bh1, bh2, h0j;
            if (isf32) {
                bi0 = ((const float*)bih)[j]; bi1 = ((const float*)bih)[j + H]; bi2 = ((const float*)bih)[j + 2 * H];
                bh0 = ((const float*)bhh)[j]; bh1 = ((const float*)bhh)[j + H]; bh2 = ((const float*)bhh)[j + 2 * H];
                h0j = ((const float*)h0)[j];
            } else {
                const __hip_bfloat16* bi = (const __hip_bfloat16*)bih;
                const __hip_bfloat16* bh = (const __hip_bfloat16*)bhh;
                bi0 = __bfloat162float(bi[j]); bi1 = __bfloat162float(bi[j + H]); bi2 = __bfloat162float(bi[j + 2 * H]);
                bh0 = __bfloat162float(bh[j]); bh1 = __bfloat162float(bh[j + H]); bh2 = __bfloat162float(bh[j + 2 * H]);
                h0j = __bfloat162float(((const __hip_bfloat16*)h0)[j]);
            }
            float b0 = ghs[j], b1 = ghs[j + 1024], b2 = ghs[j + 2048];
            float r = 1.f / (1.f + expf(-((a0 + bi0) + (b0 + bh0))));
            float z = 1.f / (1.f + expf(-((a1 + bi1) + (b1 + bh1))));
            float n = tanhf((a2 + bi2) + r * (b2 + bh2));
            float hj = (1.f - z) * n + z * h0j;
            hnew[j] = hj;
            out[(size_t)V + j] = hj;
        }
    }
    grid.sync();

    // ---------------- Stage E: logits + per-block sum(exp) ----------------
    float sumexp = 0.f;
    if (isf32) {
        const float4* hf = (const float4*)hnew;
        float4 h0v = hf[lane], h1v = hf[lane + 64], h2v = hf[lane + 128], h3v = hf[lane + 192];
        const float* W = (const float*)outw;
        const float* B = (const float*)outb;
        for (int v = gw; v < V; v += 2 * NWAVE) {  // 2-row unroll: 8 loads in flight
            const int v2 = v + NWAVE;
            const float4* w1 = (const float4*)(W + (size_t)v * H);
            float acc1 = dot4(w1[lane], h0v) + dot4(w1[lane + 64], h1v) +
                         dot4(w1[lane + 128], h2v) + dot4(w1[lane + 192], h3v);
            float acc2 = 0.f;
            if (v2 < V) {
                const float4* w2 = (const float4*)(W + (size_t)v2 * H);
                acc2 = dot4(w2[lane], h0v) + dot4(w2[lane + 64], h1v) +
                       dot4(w2[lane + 128], h2v) + dot4(w2[lane + 192], h3v);
            }
            acc1 = wred(acc1); acc2 = wred(acc2);
            if (lane == 0) {
                float val = acc1 + B[v];
                out[v] = val;
                sumexp += expf(val);
                if (v2 < V) {
                    float val2 = acc2 + B[v2];
                    out[v2] = val2;
                    sumexp += expf(val2);
                }
            }
        }
    } else {
        const float4* hf = (const float4*)hnew;
        float4 ha0 = hf[2 * lane], hb0 = hf[2 * lane + 1];
        float4 ha1 = hf[2 * (lane + 64)], hb1 = hf[2 * (lane + 64) + 1];
        const __hip_bfloat16* W = (const __hip_bfloat16*)outw;
        const __hip_bfloat16* B = (const __hip_bfloat16*)outb;
        for (int v = gw; v < V; v += 2 * NWAVE) {
            const int v2 = v + NWAVE;
            const uint4* w1 = (const uint4*)(W + (size_t)v * H);
            float acc1 = dot8f(w1[lane], ha0, hb0) + dot8f(w1[lane + 64], ha1, hb1);
            float acc2 = 0.f;
            if (v2 < V) {
                const uint4* w2 = (const uint4*)(W + (size_t)v2 * H);
                acc2 = dot8f(w2[lane], ha0, hb0) + dot8f(w2[lane + 64], ha1, hb1);
            }
            acc1 = wred(acc1); acc2 = wred(acc2);
            if (lane == 0) {
                float val = acc1 + __bfloat162float(B[v]);
                out[v] = val;
                sumexp += expf(val);
                if (v2 < V) {
                    float val2 = acc2 + __bfloat162float(B[v2]);
                    out[v2] = val2;
                    sumexp += expf(val2);
                }
            }
        }
    }
    if (lane == 0) s_part[wid] = sumexp;
    __syncthreads();
    if (tid == 0) {
        float s = 0.f;
#pragma unroll
        for (int i = 0; i < NT / 64; i++) s += s_part[i];
        S_parts[blockIdx.x] = s;
    }
    grid.sync();

    // ---------------- Stage F: out[v] -= log(sum S_parts) ----------------
    float s = S_parts[lane] + S_parts[lane + 64] + S_parts[lane + 128] + S_parts[lane + 192];
    s = wred(s);
    s = __shfl(s, 0, 64);
    float logS = logf(s);
    const int v = (int)blockIdx.x * NT + tid;  // NB*NT = 131072 >= V: one pass
    if (v < V) out[v] -= logS;
}

// =====================================================================
// FALLBACK PATH (verified 428.6 us, round-1 kernels verbatim)
// =====================================================================
__global__ __launch_bounds__(256) void k_emb_attn0(const int* __restrict__ token,
                                                   const void* __restrict__ embt,
                                                   const void* __restrict__ linw,
                                                   const void* __restrict__ linb,
                                                   const void* __restrict__ attw,
                                                   const void* __restrict__ attb,
                                                   const void* __restrict__ h0,
                                                   float* __restrict__ emb_lin,
                                                   float* __restrict__ attn_lg0,
                                                   float* __restrict__ S_parts) {
    const int lane = threadIdx.x & 63, wid = threadIdx.x >> 6;
    const int isf32 = detect_f32(embt);
    if (blockIdx.x == 0 && threadIdx.x < NSLOT) S_parts[threadIdx.x * SLOT_STRIDE] = 0.f;

    if (blockIdx.x < 256) {
        const int h = blockIdx.x * 4 + wid;
        float acc = 0.f, bias;
        if (isf32) {
            const float4* e = (const float4*)((const float*)embt + (size_t)token[0] * E);
            const float4* w = (const float4*)((const float*)linw + (size_t)h * E);
#pragma unroll
            for (int k = lane; k < 256; k += 64) acc += dot4(w[k], e[k]);
            bias = ((const float*)linb)[h];
        } else {
            const uint4* e = (const uint4*)((const __hip_bfloat16*)embt + (size_t)token[0] * E);
            const uint4* w = (const uint4*)((const __hip_bfloat16*)linw + (size_t)h * E);
#pragma unroll
            for (int k = lane; k < 128; k += 64) acc += dot8bb(w[k], e[k]);
            bias = __bfloat162float(((const __hip_bfloat16*)linb)[h]);
        }
        acc = wred(acc);
        if (lane == 0) emb_lin[h] = acc + bias;
    } else {
        const int l = (blockIdx.x - 256) * 4 + wid;
        float acc = 0.f, bias;
        if (isf32) {
            const float4* w = (const float4*)((const float*)attw + (size_t)l * 2 * H + H);
            const float4* h0f = (const float4*)(const float*)h0;
#pragma unroll
            for (int k = lane; k < 256; k += 64) acc += dot4(w[k], h0f[k]);
            bias = ((const float*)attb)[l];
        } else {
            const uint4* w = (const uint4*)((const __hip_bfloat16*)attw + (size_t)l * 2 * H + H);
            const uint4* h0u = (const uint4*)(const __hip_bfloat16*)h0;
#pragma unroll
            for (int k = lane; k < 128; k += 64) acc += dot8bb(w[k], h0u[k]);
            bias = __bfloat162float(((const __hip_bfloat16*)attb)[l]);
        }
        acc = wred(acc);
        if (lane == 0) attn_lg0[l] = acc + bias;
    }
}

__global__ __launch_bounds__(1024) void k_attn(const float* __restrict__ emb_lin,
                                               const float* __restrict__ attn_lg0,
                                               const void* __restrict__ attw,
                                               const void* __restrict__ enc,
                                               const void* __restrict__ probe,
                                               float* __restrict__ attn_app,
                                               float* __restrict__ out_attn) {
    __shared__ float lg[L];
    __shared__ float aw[L];
    const int tid = threadIdx.x, lane = tid & 63, wid = tid >> 6;
    const int isf32 = detect_f32(probe);
    const float4* ef = (const float4*)emb_lin;
    for (int l = wid; l < L; l += 16) {
        float acc = 0.f;
        if (isf32) {
            const float4* w = (const float4*)((const float*)attw + (size_t)l * 2 * H);
#pragma unroll
            for (int k = lane; k < 256; k += 64) acc += dot4(w[k], ef[k]);
        } else {
            const uint4* w = (const uint4*)((const __hip_bfloat16*)attw + (size_t)l * 2 * H);
#pragma unroll
            for (int k = lane; k < 128; k += 64) acc += dot8f(w[k], ef[2 * k], ef[2 * k + 1]);
        }
        acc = wred(acc);
        if (lane == 0) lg[l] = acc + attn_lg0[l];
    }
    __syncthreads();
    if (tid < 64) {
        float x = (tid < L) ? lg[tid] : -1e30f;
        float m = x;
#pragma unroll
        for (int o = 32; o; o >>= 1) m = fmaxf(m, __shfl_down(m, o, 64));
        m = __shfl(m, 0, 64);
        float e = (tid < L) ? expf(x - m) : 0.f;
        float s = e;
#pragma unroll
        for (int o = 32; o; o >>= 1) s += __shfl_down(s, o, 64);
        s = __shfl(s, 0, 64);
        if (tid < L) aw[tid] = e / s;
    }
    __syncthreads();
    if (tid < L) out_attn[tid] = aw[tid];
    float acc = 0.f;
    if (isf32) {
        const float* e = (const float*)enc;
        for (int l = 0; l < L; l++) acc += aw[l] * e[l * H + tid];
    } else {
        const __hip_bfloat16* e = (const __hip_bfloat16*)enc;
        for (int l = 0; l < L; l++) acc += aw[l] * __bfloat162float(e[l * H + tid]);
    }
    attn_app[tid] = acc;
}

__global__ __launch_bounds__(256) void k_comb(const float* __restrict__ cat2,
                                              const void* __restrict__ combw,
                                              const void* __restrict__ combb,
                                              const void* __restrict__ probe,
                                              float* __restrict__ xvec) {
    const int lane = threadIdx.x & 63, wid = threadIdx.x >> 6;
    const int h = blockIdx.x * 4 + wid;
    const int isf32 = detect_f32(probe);
    const float4* cf = (const float4*)cat2;
    float acc = 0.f, bias;
    if (isf32) {
        const float4* w = (const float4*)((const float*)combw + (size_t)h * 2 * H);
#pragma unroll
        for (int k = lane; k < 512; k += 64) acc += dot4(w[k], cf[k]);
        bias = ((const float*)combb)[h];
    } else {
        const uint4* w = (const uint4*)((const __hip_bfloat16*)combw + (size_t)h * 2 * H);
#pragma unroll
        for (int k = lane; k < 256; k += 64) acc += dot8f(w[k], cf[2 * k], cf[2 * k + 1]);
        bias = __bfloat162float(((const __hip_bfloat16*)combb)[h]);
    }
    acc = wred(acc);
    if (lane == 0) xvec[h] = fmaxf(acc + bias, 0.f);
}

__global__ __launch_bounds__(256) void k_gru(const float* __restrict__ xvec,
                                             const void* __restrict__ h0,
                                             const void* __restrict__ wih,
                                             const void* __restrict__ whh,
                                             const void* __restrict__ bih,
                                             const void* __restrict__ bhh,
                                             const void* __restrict__ probe,
                                             float* __restrict__ hnew,
                                             float* __restrict__ out_h) {
    const int lane = threadIdx.x & 63, wid = threadIdx.x >> 6;
    const int j = blockIdx.x * 4 + wid;
    const int isf32 = detect_f32(probe);
    const float4* xf = (const float4*)xvec;
    float a0 = 0, a1 = 0, a2 = 0, b0 = 0, b1 = 0, b2 = 0;
    float bi0, bi1, bi2, bh0, bh1, bh2, h0j;
    if (isf32) {
        const float* wi = (const float*)wih;
        const float* wh = (const float*)whh;
        const float4* wi0 = (const float4*)(wi + (size_t)j * H);
        const float4* wi1 = (const float4*)(wi + (size_t)(j + H) * H);
        const float4* wi2 = (const float4*)(wi + (size_t)(j + 2 * H) * H);
        const float4* wh0 = (const float4*)(wh + (size_t)j * H);
        const float4* wh1 = (const float4*)(wh + (size_t)(j + H) * H);
        const float4* wh2 = (const float4*)(wh + (size_t)(j + 2 * H) * H);
        const float4* h0f = (const float4*)(const float*)h0;
#pragma unroll
        for (int k = lane; k < 256; k += 64) {
            float4 xa = xf[k];
            a0 += dot4(wi0[k], xa); a1 += dot4(wi1[k], xa); a2 += dot4(wi2[k], xa);
            float4 hv = h0f[k];
            b0 += dot4(wh0[k], hv); b1 += dot4(wh1[k], hv); b2 += dot4(wh2[k], hv);
        }
        bi0 = ((const float*)bih)[j]; bi1 = ((const float*)bih)[j + H]; bi2 = ((const float*)bih)[j + 2 * H];
        bh0 = ((const float*)bhh)[j]; bh1 = ((const float*)bhh)[j + H]; bh2 = ((const float*)bhh)[j + 2 * H];
        h0j = ((const float*)h0)[j];
    } else {
        const __hip_bfloat16* wi = (const __hip_bfloat16*)wih;
        const __hip_bfloat16* wh = (const __hip_bfloat16*)whh;
        const uint4* wi0 = (const uint4*)(wi + (size_t)j * H);
        const uint4* wi1 = (const uint4*)(wi + (size_t)(j + H) * H);
        const uint4* wi2 = (const uint4*)(wi + (size_t)(j + 2 * H) * H);
        const uint4* wh0 = (const uint4*)(wh + (size_t)j * H);
        const uint4* wh1 = (const uint4*)(wh + (size_t)(j + H) * H);
        const uint4* wh2 = (const uint4*)(wh + (size_t)(j + 2 * H) * H);
        const uint4* h0u = (const uint4*)(const __hip_bfloat16*)h0;
#pragma unroll
        for (int k = lane; k < 128; k += 64) {
            float4 xa = xf[2 * k], xb = xf[2 * k + 1];
            a0 += dot8f(wi0[k], xa, xb); a1 += dot8f(wi1[k], xa, xb); a2 += dot8f(wi2[k], xa, xb);
            uint4 hv = h0u[k];
            b0 += dot8bb(wh0[k], hv); b1 += dot8bb(wh1[k], hv); b2 += dot8bb(wh2[k], hv);
        }
        const __hip_bfloat16* bi = (const __hip_bfloat16*)bih;
        const __hip_bfloat16* bh = (const __hip_bfloat16*)bhh;
        bi0 = __bfloat162float(bi[j]); bi1 = __bfloat162float(bi[j + H]); bi2 = __bfloat162float(bi[j + 2 * H]);
        bh0 = __bfloat162float(bh[j]); bh1 = __bfloat162float(bh[j + H]); bh2 = __bfloat162float(bh[j + 2 * H]);
        h0j = __bfloat162float(((const __hip_bfloat16*)h0)[j]);
    }
    a0 = wred(a0); a1 = wred(a1); a2 = wred(a2);
    b0 = wred(b0); b1 = wred(b1); b2 = wred(b2);
    if (lane == 0) {
        float r = 1.f / (1.f + expf(-((a0 + bi0) + (b0 + bh0))));
        float z = 1.f / (1.f + expf(-((a1 + bi1) + (b1 + bh1))));
        float n = tanhf((a2 + bi2) + r * (b2 + bh2));
        float hj = (1.f - z) * n + z * h0j;
        hnew[j] = hj;
        out_h[j] = hj;
    }
}

__global__ __launch_bounds__(256) void k_logits(const float* __restrict__ hnew,
                                                const void* __restrict__ outw,
                                                const void* __restrict__ outb,
                                                const void* __restrict__ probe,
                                                float* __restrict__ out,
                                                float* __restrict__ S_parts) {
    const int lane = threadIdx.x & 63, wid = threadIdx.x >> 6;
    const int v = blockIdx.x * 4 + wid;
    const int isf32 = detect_f32(probe);
    __shared__ float part[4];
    float acc = 0.f, bias = 0.f;
    if (v < V) {
        if (isf32) {
            const float4* w = (const float4*)((const float*)outw + (size_t)v * H);
            const float4* hf = (const float4*)hnew;
#pragma unroll
            for (int k = lane; k < 256; k += 64) acc += dot4(w[k], hf[k]);
            bias = ((const float*)outb)[v];
        } else {
            const uint4* w = (const uint4*)((const __hip_bfloat16*)outw + (size_t)v * H);
            const float4* hf = (const float4*)hnew;
#pragma unroll
            for (int k = lane; k < 128; k += 64) acc += dot8f(w[k], hf[2 * k], hf[2 * k + 1]);
            bias = __bfloat162float(((const __hip_bfloat16*)outb)[v]);
        }
    }
    acc = wred(acc);
    if (lane == 0) {
        float e = 0.f;
        if (v < V) {
            float val = acc + bias;
            out[v] = val;
            e = expf(val);
        }
        part[wid] = e;
    }
    __syncthreads();
    if (threadIdx.x == 0)
        atomicAdd(&S_parts[(blockIdx.x & (NSLOT - 1)) * SLOT_STRIDE],
                  part[0] + part[1] + part[2] + part[3]);
}

__global__ __launch_bounds__(256) void k_final(const float* __restrict__ S_parts,
                                               float* __restrict__ out) {
    __shared__ float lsS;
    const int tid = threadIdx.x;
    if (tid < 64) {
        float s = S_parts[tid * SLOT_STRIDE];
#pragma unroll
        for (int o = 32; o; o >>= 1) s += __shfl_down(s, o, 64);
        if (tid == 0) lsS = logf(s);
    }
    __syncthreads();
    const int v = blockIdx.x * 256 + tid;
    if (v < V) out[v] -= lsS;
}

extern "C" void kernel_launch(void* const* d_in, const int* in_sizes, int n_in,
                              void* d_out, int out_size, void* d_ws, size_t ws_size,
                              hipStream_t stream) {
    const int* token = (const int*)d_in[0];
    const void* hidden = d_in[1];
    const void* enc = d_in[2];
    const void* embt = d_in[3];
    const void* linw = d_in[4];
    const void* linb = d_in[5];
    const void* attw = d_in[6];
    const void* attb = d_in[7];
    const void* combw = d_in[8];
    const void* combb = d_in[9];
    const void* wih = d_in[10];
    const void* whh = d_in[11];
    const void* bih = d_in[12];
    const void* bhh = d_in[13];
    const void* outw = d_in[14];
    const void* outb = d_in[15];
    float* out = (float*)d_out;
    float* wsf = (float*)d_ws;

    // --- preferred: single cooperative mega-kernel ---
    void* args[] = {(void*)&token, (void*)&hidden, (void*)&enc, (void*)&embt,
                    (void*)&linw, (void*)&linb, (void*)&attw, (void*)&attb,
                    (void*)&combw, (void*)&combb, (void*)&wih, (void*)&whh,
                    (void*)&bih, (void*)&bhh, (void*)&outw, (void*)&outb,
                    (void*)&out, (void*)&wsf};
    hipError_t err = hipLaunchCooperativeKernel((void*)k_mega, dim3(NB), dim3(NT),
                                                args, 0, stream);
    if (err == hipSuccess) return;

    // --- fallback: verified 6-kernel path (round-1, 428.6 us) ---
    float* S_parts = wsf;
    float* emb_lin = wsf + 512;
    float* attn_app = wsf + 512 + 1024;
    float* xvec = wsf + 512 + 2048;
    float* hnew = wsf + 512 + 3072;
    float* attn_lg0 = wsf + 512 + 4096;
    float* cat2 = emb_lin;

    k_emb_attn0<<<269, 256, 0, stream>>>(token, embt, linw, linb, attw, attb, hidden,
                                         emb_lin, attn_lg0, S_parts);
    k_attn<<<1, 1024, 0, stream>>>(emb_lin, attn_lg0, attw, enc, embt, attn_app,
                                   out + (V + H));
    k_comb<<<256, 256, 0, stream>>>(cat2, combw, combb, embt, xvec);
    k_gru<<<256, 256, 0, stream>>>(xvec, hidden, wih, whh, bih, bhh, embt, hnew, out + V);
    k_logits<<<(V + 3) / 4, 256, 0, stream>>>(hnew, outw, outb, embt, out, S_parts);
    k_final<<<(V + 255) / 256, 256, 0, stream>>>(S_parts, out);
}

// Round 3
// 426.843 us; speedup vs baseline: 1.4246x; 1.4246x over previous
//
#include <hip/hip_runtime.h>
#include <hip/hip_bf16.h>
#include <stdint.h>

#define V 50257
#define E 1024
#define H 1024
#define L 52

// 64 atomic slots, 32 B apart (8 floats) to spread same-line contention.
#define NSLOT 64
#define SLOT_STRIDE 8

// ---------- helpers ----------
__device__ __forceinline__ float bf_lo(uint32_t u) { return __uint_as_float(u << 16); }
__device__ __forceinline__ float bf_hi(uint32_t u) { return __uint_as_float(u & 0xffff0000u); }

__device__ __forceinline__ float dot4(float4 a, float4 b) {
    return a.x * b.x + a.y * b.y + a.z * b.z + a.w * b.w;
}
// dot of 8 bf16 (packed in uint4) with 8 f32 (two float4)
__device__ __forceinline__ float dot8f(uint4 u, float4 a, float4 b) {
    return bf_lo(u.x) * a.x + bf_hi(u.x) * a.y + bf_lo(u.y) * a.z + bf_hi(u.y) * a.w +
           bf_lo(u.z) * b.x + bf_hi(u.z) * b.y + bf_lo(u.w) * b.z + bf_hi(u.w) * b.w;
}
// dot of 8 bf16 with 8 bf16
__device__ __forceinline__ float dot8bb(uint4 u, uint4 v) {
    return bf_lo(u.x) * bf_lo(v.x) + bf_hi(u.x) * bf_hi(v.x) +
           bf_lo(u.y) * bf_lo(v.y) + bf_hi(u.y) * bf_hi(v.y) +
           bf_lo(u.z) * bf_lo(v.z) + bf_hi(u.z) * bf_hi(v.z) +
           bf_lo(u.w) * bf_lo(v.w) + bf_hi(u.w) * bf_hi(v.w);
}

__device__ __forceinline__ float wred(float v) {
#pragma unroll
    for (int o = 32; o; o >>= 1) v += __shfl_down(v, o, 64);
    return v;  // valid in lane 0
}

// Inline dtype detect: probe 64 words of the embedding table. For a true-f32
// buffer the low-16-bit halves decode as bf16 garbage; for bf16 params none
// do. 256 B L2-broadcast read, wave-uniform result. Full wave, no divergence.
__device__ __forceinline__ int detect_f32(const void* probe) {
    uint32_t u = ((const uint32_t*)probe)[threadIdx.x & 63];
    float lo = __uint_as_float(u << 16);
    int bad = (lo != lo) || (fabsf(lo) > 100.f);
    unsigned long long m = __ballot(bad);
    return (__popcll(m) > 4) ? 1 : 0;
}

// ---------- K1 (front): three independent GEMV groups + slot zeroing ----------
// blocks 0..255    : emb_lin rows  (emb = emb_table[token] @ linear_w.T + b)
// blocks 256..268  : attn logits h0-half: lg0[l] = attn_w[l,H:] @ h0 + attb[l]
// blocks 269..1036 : gru gh rows:  ghs[r]  = whh[r,:] @ h0   (r = 0..3071)
__global__ __launch_bounds__(256) void k_front(const int* __restrict__ token,
                                               const void* __restrict__ embt,
                                               const void* __restrict__ linw,
                                               const void* __restrict__ linb,
                                               const void* __restrict__ attw,
                                               const void* __restrict__ attb,
                                               const void* __restrict__ whh,
                                               const void* __restrict__ h0,
                                               float* __restrict__ emb_lin,
                                               float* __restrict__ attn_lg0,
                                               float* __restrict__ ghs,
                                               float* __restrict__ S_parts) {
    const int lane = threadIdx.x & 63, wid = threadIdx.x >> 6;
    const int b = blockIdx.x;
    const int isf32 = detect_f32(embt);
    if (b == 0 && threadIdx.x < NSLOT) S_parts[threadIdx.x * SLOT_STRIDE] = 0.f;

    if (b < 256) {
        const int h = b * 4 + wid;
        float acc = 0.f, bias;
        if (isf32) {
            const float4* e = (const float4*)((const float*)embt + (size_t)token[0] * E);
            const float4* w = (const float4*)((const float*)linw + (size_t)h * E);
#pragma unroll
            for (int k = lane; k < 256; k += 64) acc += dot4(w[k], e[k]);
            bias = ((const float*)linb)[h];
        } else {
            const uint4* e = (const uint4*)((const __hip_bfloat16*)embt + (size_t)token[0] * E);
            const uint4* w = (const uint4*)((const __hip_bfloat16*)linw + (size_t)h * E);
#pragma unroll
            for (int k = lane; k < 128; k += 64) acc += dot8bb(w[k], e[k]);
            bias = __bfloat162float(((const __hip_bfloat16*)linb)[h]);
        }
        acc = wred(acc);
        if (lane == 0) emb_lin[h] = acc + bias;
    } else if (b < 269) {
        const int l = (b - 256) * 4 + wid;  // 13*4 = 52 rows exactly
        float acc = 0.f, bias;
        if (isf32) {
            const float4* w = (const float4*)((const float*)attw + (size_t)l * 2 * H + H);
            const float4* h0f = (const float4*)(const float*)h0;
#pragma unroll
            for (int k = lane; k < 256; k += 64) acc += dot4(w[k], h0f[k]);
            bias = ((const float*)attb)[l];
        } else {
            const uint4* w = (const uint4*)((const __hip_bfloat16*)attw + (size_t)l * 2 * H + H);
            const uint4* h0u = (const uint4*)(const __hip_bfloat16*)h0;
#pragma unroll
            for (int k = lane; k < 128; k += 64) acc += dot8bb(w[k], h0u[k]);
            bias = __bfloat162float(((const __hip_bfloat16*)attb)[l]);
        }
        acc = wred(acc);
        if (lane == 0) attn_lg0[l] = acc + bias;
    } else {
        const int r = (b - 269) * 4 + wid;  // 768*4 = 3072 rows exactly
        float acc = 0.f;
        if (isf32) {
            const float4* w = (const float4*)((const float*)whh + (size_t)r * H);
            const float4* h0f = (const float4*)(const float*)h0;
#pragma unroll
            for (int k = lane; k < 256; k += 64) acc += dot4(w[k], h0f[k]);
        } else {
            const uint4* w = (const uint4*)((const __hip_bfloat16*)whh + (size_t)r * H);
            const uint4* h0u = (const uint4*)(const __hip_bfloat16*)h0;
#pragma unroll
            for (int k = lane; k < 128; k += 64) acc += dot8bb(w[k], h0u[k]);
        }
        acc = wred(acc);
        if (lane == 0) ghs[r] = acc;
    }
}

// ---------- K2: attn logits (emb half) + softmax + context (single block) ----------
__global__ __launch_bounds__(1024) void k_attn(const float* __restrict__ emb_lin,
                                               const float* __restrict__ attn_lg0,
                                               const void* __restrict__ attw,
                                               const void* __restrict__ enc,
                                               const void* __restrict__ probe,
                                               float* __restrict__ attn_app,
                                               float* __restrict__ out_attn) {
    __shared__ float lg[L];
    __shared__ float aw[L];
    const int tid = threadIdx.x, lane = tid & 63, wid = tid >> 6;
    const int isf32 = detect_f32(probe);
    const float4* ef = (const float4*)emb_lin;
    for (int l = wid; l < L; l += 16) {
        float acc = 0.f;
        if (isf32) {
            const float4* w = (const float4*)((const float*)attw + (size_t)l * 2 * H);
#pragma unroll
            for (int k = lane; k < 256; k += 64) acc += dot4(w[k], ef[k]);
        } else {
            const uint4* w = (const uint4*)((const __hip_bfloat16*)attw + (size_t)l * 2 * H);
#pragma unroll
            for (int k = lane; k < 128; k += 64) acc += dot8f(w[k], ef[2 * k], ef[2 * k + 1]);
        }
        acc = wred(acc);
        if (lane == 0) lg[l] = acc + attn_lg0[l];
    }
    __syncthreads();
    if (tid < 64) {  // wave-parallel softmax over 52 logits
        float x = (tid < L) ? lg[tid] : -1e30f;
        float m = x;
#pragma unroll
        for (int o = 32; o; o >>= 1) m = fmaxf(m, __shfl_down(m, o, 64));
        m = __shfl(m, 0, 64);
        float e = (tid < L) ? expf(x - m) : 0.f;
        float s = e;
#pragma unroll
        for (int o = 32; o; o >>= 1) s += __shfl_down(s, o, 64);
        s = __shfl(s, 0, 64);
        if (tid < L) aw[tid] = e / s;
    }
    __syncthreads();
    if (tid < L) out_attn[tid] = aw[tid];
    // attn_applied[h] = sum_l aw[l] * enc[l,h]  (coalesced over h = tid)
    float acc = 0.f;
    if (isf32) {
        const float* e = (const float*)enc;
        for (int l = 0; l < L; l++) acc += aw[l] * e[l * H + tid];
    } else {
        const __hip_bfloat16* e = (const __hip_bfloat16*)enc;
        for (int l = 0; l < L; l++) acc += aw[l] * __bfloat162float(e[l * H + tid]);
    }
    attn_app[tid] = acc;
}

// ---------- K3: x = relu(cat(emb, attn_app) @ comb_w.T + comb_b) ----------
__global__ __launch_bounds__(256) void k_comb(const float* __restrict__ cat2,  // 2048 f32
                                              const void* __restrict__ combw,
                                              const void* __restrict__ combb,
                                              const void* __restrict__ probe,
                                              float* __restrict__ xvec) {
    const int lane = threadIdx.x & 63, wid = threadIdx.x >> 6;
    const int h = blockIdx.x * 4 + wid;
    const int isf32 = detect_f32(probe);
    const float4* cf = (const float4*)cat2;
    float acc = 0.f, bias;
    if (isf32) {
        const float4* w = (const float4*)((const float*)combw + (size_t)h * 2 * H);
#pragma unroll
        for (int k = lane; k < 512; k += 64) acc += dot4(w[k], cf[k]);
        bias = ((const float*)combb)[h];
    } else {
        const uint4* w = (const uint4*)((const __hip_bfloat16*)combw + (size_t)h * 2 * H);
#pragma unroll
        for (int k = lane; k < 256; k += 64) acc += dot8f(w[k], cf[2 * k], cf[2 * k + 1]);
        bias = __bfloat162float(((const __hip_bfloat16*)combb)[h]);
    }
    acc = wred(acc);
    if (lane == 0) xvec[h] = fmaxf(acc + bias, 0.f);
}

// ---------- K4: gru gi-half (wih @ x) + gate combine (gh read from ws) ----------
__global__ __launch_bounds__(256) void k_gru(const float* __restrict__ xvec,
                                             const void* __restrict__ h0,
                                             const void* __restrict__ wih,
                                             const void* __restrict__ bih,
                                             const void* __restrict__ bhh,
                                             const float* __restrict__ ghs,
                                             const void* __restrict__ probe,
                                             float* __restrict__ hnew,
                                             float* __restrict__ out_h) {
    const int lane = threadIdx.x & 63, wid = threadIdx.x >> 6;
    const int j = blockIdx.x * 4 + wid;
    const int isf32 = detect_f32(probe);
    const float4* xf = (const float4*)xvec;
    float a0 = 0, a1 = 0, a2 = 0;
    if (isf32) {
        const float* wi = (const float*)wih;
        const float4* wi0 = (const float4*)(wi + (size_t)j * H);
        const float4* wi1 = (const float4*)(wi + (size_t)(j + H) * H);
        const float4* wi2 = (const float4*)(wi + (size_t)(j + 2 * H) * H);
#pragma unroll
        for (int k = lane; k < 256; k += 64) {
            float4 xa = xf[k];
            a0 += dot4(wi0[k], xa); a1 += dot4(wi1[k], xa); a2 += dot4(wi2[k], xa);
        }
    } else {
        const __hip_bfloat16* wi = (const __hip_bfloat16*)wih;
        const uint4* wi0 = (const uint4*)(wi + (size_t)j * H);
        const uint4* wi1 = (const uint4*)(wi + (size_t)(j + H) * H);
        const uint4* wi2 = (const uint4*)(wi + (size_t)(j + 2 * H) * H);
#pragma unroll
        for (int k = lane; k < 128; k += 64) {
            float4 xa = xf[2 * k], xb = xf[2 * k + 1];
            a0 += dot8f(wi0[k], xa, xb); a1 += dot8f(wi1[k], xa, xb); a2 += dot8f(wi2[k], xa, xb);
        }
    }
    a0 = wred(a0); a1 = wred(a1); a2 = wred(a2);
    if (lane == 0) {
        float bi0, bi1, bi2, bh0, bh1, bh2, h0j;
        if (isf32) {
            bi0 = ((const float*)bih)[j]; bi1 = ((const float*)bih)[j + H]; bi2 = ((const float*)bih)[j + 2 * H];
            bh0 = ((const float*)bhh)[j]; bh1 = ((const float*)bhh)[j + H]; bh2 = ((const float*)bhh)[j + 2 * H];
            h0j = ((const float*)h0)[j];
        } else {
            const __hip_bfloat16* bi = (const __hip_bfloat16*)bih;
            const __hip_bfloat16* bh = (const __hip_bfloat16*)bhh;
            bi0 = __bfloat162float(bi[j]); bi1 = __bfloat162float(bi[j + H]); bi2 = __bfloat162float(bi[j + 2 * H]);
            bh0 = __bfloat162float(bh[j]); bh1 = __bfloat162float(bh[j + H]); bh2 = __bfloat162float(bh[j + 2 * H]);
            h0j = __bfloat162float(((const __hip_bfloat16*)h0)[j]);
        }
        float b0 = ghs[j], b1 = ghs[j + 1024], b2 = ghs[j + 2048];
        float r = 1.f / (1.f + expf(-((a0 + bi0) + (b0 + bh0))));
        float z = 1.f / (1.f + expf(-((a1 + bi1) + (b1 + bh1))));
        float n = tanhf((a2 + bi2) + r * (b2 + bh2));
        float hj = (1.f - z) * n + z * h0j;
        hnew[j] = hj;
        out_h[j] = hj;
    }
}

// ---------- K5: logits (f32) into out[0..V) + fused partial sum of exp ----------
__global__ __launch_bounds__(256) void k_logits(const float* __restrict__ hnew,
                                                const void* __restrict__ outw,
                                                const void* __restrict__ outb,
                                                const void* __restrict__ probe,
                                                float* __restrict__ out,
                                                float* __restrict__ S_parts) {
    const int lane = threadIdx.x & 63, wid = threadIdx.x >> 6;
    const int v = blockIdx.x * 4 + wid;
    const int isf32 = detect_f32(probe);
    __shared__ float part[4];
    float acc = 0.f, bias = 0.f;
    if (v < V) {  // wave-uniform guard (only tail waves of last block skip)
        if (isf32) {
            const float4* w = (const float4*)((const float*)outw + (size_t)v * H);
            const float4* hf = (const float4*)hnew;
#pragma unroll
            for (int k = lane; k < 256; k += 64) acc += dot4(w[k], hf[k]);
            bias = ((const float*)outb)[v];
        } else {
            const uint4* w = (const uint4*)((const __hip_bfloat16*)outw + (size_t)v * H);
            const float4* hf = (const float4*)hnew;
#pragma unroll
            for (int k = lane; k < 128; k += 64) acc += dot8f(w[k], hf[2 * k], hf[2 * k + 1]);
            bias = __bfloat162float(((const __hip_bfloat16*)outb)[v]);
        }
    }
    acc = wred(acc);
    if (lane == 0) {
        float e = 0.f;
        if (v < V) {
            float val = acc + bias;
            out[v] = val;
            e = expf(val);
        }
        part[wid] = e;
    }
    __syncthreads();
    if (threadIdx.x == 0)
        atomicAdd(&S_parts[(blockIdx.x & (NSLOT - 1)) * SLOT_STRIDE],
                  part[0] + part[1] + part[2] + part[3]);
}

// ---------- K6: out = logits - log(sum S_parts), in place (f32) ----------
__global__ __launch_bounds__(256) void k_final(const float* __restrict__ S_parts,
                                               float* __restrict__ out) {
    __shared__ float lsS;
    const int tid = threadIdx.x;
    if (tid < 64) {
        float s = S_parts[tid * SLOT_STRIDE];
#pragma unroll
        for (int o = 32; o; o >>= 1) s += __shfl_down(s, o, 64);
        if (tid == 0) lsS = logf(s);
    }
    __syncthreads();
    const int v = blockIdx.x * 256 + tid;
    if (v < V) out[v] -= lsS;
}

extern "C" void kernel_launch(void* const* d_in, const int* in_sizes, int n_in,
                              void* d_out, int out_size, void* d_ws, size_t ws_size,
                              hipStream_t stream) {
    const int* token = (const int*)d_in[0];
    const void* hidden = d_in[1];
    const void* enc = d_in[2];
    const void* embt = d_in[3];
    const void* linw = d_in[4];
    const void* linb = d_in[5];
    const void* attw = d_in[6];
    const void* attb = d_in[7];
    const void* combw = d_in[8];
    const void* combb = d_in[9];
    const void* wih = d_in[10];
    const void* whh = d_in[11];
    const void* bih = d_in[12];
    const void* bhh = d_in[13];
    const void* outw = d_in[14];
    const void* outb = d_in[15];
    float* out = (float*)d_out;  // f32 output: [0,V)=log_probs, [V,V+H)=h_new, [V+H,+L)=attn_w

    // ws layout (floats):
    // [0 .. 512)      : S_parts (64 slots, stride 8)
    // [512 .. 1536)   : emb_lin (1024)          } contiguous -> cat2 for k_comb
    // [1536 .. 2560)  : attn_app (1024)         }
    // [2560 .. 3584)  : xvec (1024)
    // [3584 .. 4608)  : hnew (1024)
    // [4608 .. 4672)  : attn_lg0 (52)
    // [4672 .. 7744)  : ghs (3072, whh @ h0 flat rows)
    // Total ~31 KB.
    float* ws = (float*)d_ws;
    float* S_parts = ws;
    float* emb_lin = ws + 512;
    float* attn_app = ws + 512 + 1024;
    float* xvec = ws + 512 + 2048;
    float* hnew = ws + 512 + 3072;
    float* attn_lg0 = ws + 512 + 4096;
    float* ghs = ws + 512 + 4160;
    float* cat2 = emb_lin;  // [emb_lin | attn_app] contiguous 2048 floats

    k_front<<<1037, 256, 0, stream>>>(token, embt, linw, linb, attw, attb, whh, hidden,
                                      emb_lin, attn_lg0, ghs, S_parts);
    k_attn<<<1, 1024, 0, stream>>>(emb_lin, attn_lg0, attw, enc, embt, attn_app,
                                   out + (V + H));
    k_comb<<<256, 256, 0, stream>>>(cat2, combw, combb, embt, xvec);
    k_gru<<<256, 256, 0, stream>>>(xvec, hidden, wih, bih, bhh, ghs, embt, hnew, out + V);
    k_logits<<<(V + 3) / 4, 256, 0, stream>>>(hnew, outw, outb, embt, out, S_parts);
    k_final<<<(V + 255) / 256, 256, 0, stream>>>(S_parts, out);
}